// Round 1
// baseline (849.915 us; speedup 1.0000x reference)
//
#include <hip/hip_runtime.h>
#include <cstdint>

// Problem constants
#define NB 8
#define NL 4096
#define NC 64
#define NWIN 4
#define NHEAD 4
#define DD 576   // C*K*K

// ws float offsets
#define OFF_AQK   0         // 128*81 sums (atomic)
#define OFF_KV    10368     // 32*576 (atomic)
#define OFF_K2O   28800     // 32*576 (atomic)
#define ZERO_FLOATS 47232
#define OFF_KERN0 47232     // 32*576
#define OFF_KERNM 65664     // 32*576
#define OFF_WW    84096     // 32
#define OFF_WT    84128     // 32
#define OFF_F2    84160     // [b][c][9][64] = 294912

// ---------------------------------------------------------------------------
// K1: adaptive pool attn (128 mats of 1024x1024) -> per-mat 9x9 SUMS (atomic)
// bins: elem c in bin p=(c*9)>>10, and also bin p+1 iff c == ((p+1)*1024)/9
// ---------------------------------------------------------------------------
__global__ __launch_bounds__(256) void k_attn_pool(const float* __restrict__ attn,
                                                   float* __restrict__ aqk_sum) {
    __shared__ float acc[81];
    int t = threadIdx.x;
    if (t < 81) acc[t] = 0.f;
    __syncthreads();

    int mat = blockIdx.x >> 4;          // 0..127
    int chunk = blockIdx.x & 15;        // 64 rows each
    int wave = t >> 6, lane = t & 63;
    const float* base = attn + (size_t)mat * 1024u * 1024u;
    int c0 = lane * 16;
    int b0 = (c0 * 9) >> 10;            // col bin of lane's first element

    for (int rr = 0; rr < 16; ++rr) {
        int r = chunk * 64 + wave * 16 + rr;
        const float4* row = reinterpret_cast<const float4*>(base + (size_t)r * 1024 + c0);
        float a0 = 0.f, a1 = 0.f;
#pragma unroll
        for (int u = 0; u < 4; ++u) {
            float4 v = row[u];
            float vals[4] = {v.x, v.y, v.z, v.w};
#pragma unroll
            for (int e = 0; e < 4; ++e) {
                int c = c0 + u * 4 + e;
                float val = vals[e];
                int p = (c * 9) >> 10;
                if (p == b0) a0 += val; else a1 += val;
                int ns = ((p + 1) << 10) / 9;     // start of bin p+1
                if (c == ns) a1 += val;            // shared element (p==b0 always here)
            }
        }
        int rp = (r * 9) >> 10;
        int rs = ((rp + 1) << 10) / 9;
        atomicAdd(&acc[rp * 9 + b0], a0);
        if (a1 != 0.f && b0 < 8) atomicAdd(&acc[rp * 9 + b0 + 1], a1);
        if (r == rs && rp < 8) {
            atomicAdd(&acc[(rp + 1) * 9 + b0], a0);
            if (a1 != 0.f && b0 < 8) atomicAdd(&acc[(rp + 1) * 9 + b0 + 1], a1);
        }
    }
    __syncthreads();
    if (t < 81) {
        float v = acc[t];
        if (v != 0.f) atomicAdd(&aqk_sum[mat * 81 + t], v);
    }
}

// ---------------------------------------------------------------------------
// K2: per-window 32x32 -> 3x3 adaptive pool (kern0, layout [win][c*9+kk]) and
//     ww[b*4+nw] = sum_c mean(window)*down_w[nw][c] + down_b[nw]
// ---------------------------------------------------------------------------
__global__ __launch_bounds__(640) void k_win_pool(const float* __restrict__ x,
                                                  const float* __restrict__ down_w,
                                                  const float* __restrict__ down_b,
                                                  float* __restrict__ kern0,
                                                  float* __restrict__ ww) {
    int blk = blockIdx.x;              // b*4+nw
    int b = blk >> 2, nw = blk & 3;
    int wr = nw >> 1, wc = nw & 1;
    int wave = threadIdx.x >> 6, c = threadIdx.x & 63;
    const float* xb = x + (size_t)b * NL * NC;

    if (wave < 9) {
        int ki = wave / 3, kj = wave % 3;
        int si = (ki * 32) / 3, ei = ((ki + 1) * 32 + 2) / 3;
        int sj = (kj * 32) / 3, ej = ((kj + 1) * 32 + 2) / 3;
        float s = 0.f;
        for (int i = si; i < ei; ++i)
            for (int j = sj; j < ej; ++j)
                s += xb[((size_t)((wr * 32 + i) * 64) + wc * 32 + j) * 64 + c];
        float cnt = (float)((ei - si) * (ej - sj));
        kern0[blk * DD + c * 9 + wave] = s / cnt;
    } else {
        float s = 0.f;
        for (int i = 0; i < 32; ++i)
            for (int j = 0; j < 32; ++j)
                s += xb[((size_t)((wr * 32 + i) * 64) + wc * 32 + j) * 64 + c];
        float v = (s * (1.f / 1024.f)) * down_w[nw * 64 + c];
#pragma unroll
        for (int off = 32; off; off >>= 1) v += __shfl_down(v, off);
        if (c == 0) ww[blk] = v + down_b[nw];
    }
}

// ---------------------------------------------------------------------------
// K2b: tiny MLP: ww(4) -> gelu(lin1) -> sigmoid(lin2) -> weight (per batch)
// ---------------------------------------------------------------------------
__global__ void k_mlp(const float* __restrict__ ww,
                      const float* __restrict__ lin1_w, const float* __restrict__ lin1_b,
                      const float* __restrict__ lin2_w, const float* __restrict__ lin2_b,
                      float* __restrict__ weight) {
    int b = threadIdx.x;
    if (b >= NB) return;
    float w0[4];
#pragma unroll
    for (int n = 0; n < 4; ++n) w0[n] = ww[b * 4 + n];
    float acc2[4];
#pragma unroll
    for (int n = 0; n < 4; ++n) acc2[n] = lin2_b[n];
    for (int j = 0; j < 16; ++j) {
        float h = lin1_b[j];
#pragma unroll
        for (int n = 0; n < 4; ++n) h += w0[n] * lin1_w[j * 4 + n];
        h = 0.5f * h * (1.f + erff(h * 0.70710678118654752440f));   // exact gelu
#pragma unroll
        for (int n = 0; n < 4; ++n) acc2[n] += h * lin2_w[n * 16 + j];
    }
#pragma unroll
    for (int n = 0; n < 4; ++n) weight[b * 4 + n] = 1.f / (1.f + expf(-acc2[n]));
}

// ---------------------------------------------------------------------------
// K3a/K3c: out(32x576) += A(32x576) @ W(576x576)^T  (+bias on ic==0), atomics
// grid 81: oc = %9 (64-col out chunk), ic = /9 (64-wide K chunk)
// ---------------------------------------------------------------------------
__global__ __launch_bounds__(256) void k_mm576(const float* __restrict__ A,
                                               const float* __restrict__ Wm,
                                               const float* __restrict__ bias,
                                               float* __restrict__ out) {
    __shared__ float Ws[64][65];
    __shared__ float As[32][65];
    int oc = blockIdx.x % 9, ic = blockIdx.x / 9;
    int o0 = oc * 64, i0 = ic * 64;
    int t = threadIdx.x;
    for (int idx = t; idx < 64 * 64; idx += 256) {
        int j = idx >> 6, ii = idx & 63;
        Ws[j][ii] = Wm[(size_t)(o0 + j) * DD + i0 + ii];
    }
    for (int idx = t; idx < 32 * 64; idx += 256) {
        int r = idx >> 6, ii = idx & 63;
        As[r][ii] = A[r * DD + i0 + ii];
    }
    __syncthreads();
    int j = t & 63, rg = t >> 6;
    float acc[8];
#pragma unroll
    for (int q = 0; q < 8; ++q) acc[q] = 0.f;
    for (int ii = 0; ii < 64; ++ii) {
        float w = Ws[j][ii];
#pragma unroll
        for (int q = 0; q < 8; ++q) acc[q] += As[rg * 8 + q][ii] * w;
    }
    float bo = (ic == 0) ? bias[o0 + j] : 0.f;
#pragma unroll
    for (int q = 0; q < 8; ++q)
        atomicAdd(&out[(rg * 8 + q) * DD + o0 + j], acc[q] + bo);
}

// ---------------------------------------------------------------------------
// K3b: kernM[b][n][i*144+dh*9+k2] = sum_q aqk_mean[f][k2][q] * kvT[f][q][dh]
//      f = b*16 + i*4 + n ; kvT[f][q][dh] = kv[(b*4+i)*576 + n*144 + dh*9 + q]
// ---------------------------------------------------------------------------
__global__ __launch_bounds__(576) void k_pmm(const float* __restrict__ aqk_sum,
                                             const float* __restrict__ kv,
                                             float* __restrict__ kernM) {
    int blk = blockIdx.x;             // b*4 + n
    int b = blk >> 2, n = blk & 3;
    int d = threadIdx.x;              // 0..575
    int i = d / 144, rem = d % 144, dh = rem / 9, k2 = rem % 9;
    int f = b * 16 + i * 4 + n;
    int sk = (k2 * 1024) / 9, ek = ((k2 + 1) * 1024 + 8) / 9;
    float rlk = (float)(ek - sk);
    const float* aq = aqk_sum + f * 81 + k2 * 9;
    const float* kvp = kv + (b * 4 + i) * DD + n * 144 + dh * 9;
    float acc = 0.f;
#pragma unroll
    for (int q = 0; q < 9; ++q) {
        int sq = (q * 1024) / 9, eq = ((q + 1) * 1024 + 8) / 9;
        float inv = 1.f / (rlk * (float)(eq - sq));
        acc += aq[q] * inv * kvp[q];
    }
    kernM[blk * DD + d] = acc;
}

// ---------------------------------------------------------------------------
// K4: F2[b][c][kl][o] = sum_{wi<4} fw[o][wi*64+c]*k2s[wi] + fw[o][256+c]*g
//     k2s[n] = kern2[b,n,c*9+kl]*weight[b,n]; g = sum k2s[n]*gk_w[n] + gk_b
// ---------------------------------------------------------------------------
__global__ __launch_bounds__(576) void k_build_F(const float* __restrict__ kern2,
                                                 const float* __restrict__ weight,
                                                 const float* __restrict__ gk_w,
                                                 const float* __restrict__ gk_b,
                                                 const float* __restrict__ fusion_w,
                                                 float* __restrict__ F2) {
    int b = blockIdx.x;
    int d = threadIdx.x;              // c*9+kl
    int c = d / 9, kl = d % 9;
    float k2s[4];
    float g = gk_b[0];
#pragma unroll
    for (int n = 0; n < 4; ++n) {
        float v = kern2[(b * 4 + n) * DD + d] * weight[b * 4 + n];
        k2s[n] = v;
        g += v * gk_w[n];
    }
    size_t obase = (((size_t)b * 64 + c) * 9 + kl) * 64;
    for (int o = 0; o < 64; ++o) {
        float v = fusion_w[o * 320 + 256 + c] * g;
#pragma unroll
        for (int n = 0; n < 4; ++n) v += fusion_w[o * 320 + n * 64 + c] * k2s[n];
        F2[obase + o] = v;
    }
}

// ---------------------------------------------------------------------------
// K5: out[b, h*64+w, o] = fusion_b[o] + sum_{c,dk,dl} x[b,h+dk-1,w+dl-1,c]*F2[b,c,dk*3+dl,o]
// block = (b,h): 64 w x 64 o, thread = 4w x 4o. x tile transposed [dk][c][w+1].
// ---------------------------------------------------------------------------
__global__ __launch_bounds__(256) void k_conv(const float* __restrict__ x,
                                              const float* __restrict__ F2,
                                              const float* __restrict__ fusion_b,
                                              float* __restrict__ out) {
    __shared__ float As[3][16][68];     // [dk][c&15][w+1], rows padded to 68
    __shared__ float Bs[16][9][64];     // [c&15][kl][o]
    int t = threadIdx.x;
    int h = blockIdx.x & 63, b = blockIdx.x >> 6;
    int w0 = (t & 15) * 4;
    int o0 = (t >> 4) * 4;

    float acc[4][4];
#pragma unroll
    for (int wi = 0; wi < 4; ++wi)
#pragma unroll
        for (int oi = 0; oi < 4; ++oi) acc[wi][oi] = 0.f;

    for (int cq = 0; cq < 4; ++cq) {
        __syncthreads();
        // stage Bs: 16c x 9 x 64o
        for (int idx = t; idx < 16 * 9 * 64; idx += 256) {
            int o = idx & 63; int r = idx >> 6; int kl = r % 9; int cc = r / 9;
            Bs[cc][kl][o] = F2[(((size_t)b * 64 + cq * 16 + cc) * 9 + kl) * 64 + o];
        }
        // stage As (transposed, halo in w, zero-padded rows)
        for (int idx = t; idx < 3 * 64 * 4; idx += 256) {
            int gg = idx & 3; int w = (idx >> 2) & 63; int dk = idx >> 8;
            int hh = h + dk - 1;
            float4 v = make_float4(0.f, 0.f, 0.f, 0.f);
            if (hh >= 0 && hh < 64)
                v = *reinterpret_cast<const float4*>(
                    &x[(((size_t)b * 64 + hh) * 64 + w) * 64 + cq * 16 + gg * 4]);
            As[dk][gg * 4 + 0][w + 1] = v.x;
            As[dk][gg * 4 + 1][w + 1] = v.y;
            As[dk][gg * 4 + 2][w + 1] = v.z;
            As[dk][gg * 4 + 3][w + 1] = v.w;
        }
        if (t < 96) {   // zero halo columns w1=0 and w1=65
            int cc = t & 15; int dk = (t >> 4) % 3; int side = t / 48;
            As[dk][cc][side ? 65 : 0] = 0.f;
        }
        __syncthreads();

#pragma unroll
        for (int dk = 0; dk < 3; ++dk) {
#pragma unroll 4
            for (int cc = 0; cc < 16; ++cc) {
                float4 xa = *reinterpret_cast<const float4*>(&As[dk][cc][w0]);
                float xv[6];
                xv[0] = xa.x; xv[1] = xa.y; xv[2] = xa.z; xv[3] = xa.w;
                xv[4] = As[dk][cc][w0 + 4];
                xv[5] = As[dk][cc][w0 + 5];
#pragma unroll
                for (int dl = 0; dl < 3; ++dl) {
                    float4 bv = *reinterpret_cast<const float4*>(&Bs[cc][dk * 3 + dl][o0]);
#pragma unroll
                    for (int wi = 0; wi < 4; ++wi) {
                        float xx = xv[wi + dl];
                        acc[wi][0] += xx * bv.x;
                        acc[wi][1] += xx * bv.y;
                        acc[wi][2] += xx * bv.z;
                        acc[wi][3] += xx * bv.w;
                    }
                }
            }
        }
    }

    float4 fb = *reinterpret_cast<const float4*>(&fusion_b[o0]);
#pragma unroll
    for (int wi = 0; wi < 4; ++wi) {
        float4 r;
        r.x = acc[wi][0] + fb.x;
        r.y = acc[wi][1] + fb.y;
        r.z = acc[wi][2] + fb.z;
        r.w = acc[wi][3] + fb.w;
        *reinterpret_cast<float4*>(
            &out[(((size_t)b * NL) + h * 64 + w0 + wi) * 64 + o0]) = r;
    }
}

// ---------------------------------------------------------------------------
extern "C" void kernel_launch(void* const* d_in, const int* in_sizes, int n_in,
                              void* d_out, int out_size, void* d_ws, size_t ws_size,
                              hipStream_t stream) {
    const float* x         = (const float*)d_in[0];
    const float* attn      = (const float*)d_in[1];
    const float* proj_v_w  = (const float*)d_in[2];
    const float* proj_v_b  = (const float*)d_in[3];
    const float* proj_out_w= (const float*)d_in[4];
    const float* proj_out_b= (const float*)d_in[5];
    const float* down_w    = (const float*)d_in[6];
    const float* down_b    = (const float*)d_in[7];
    const float* lin1_w    = (const float*)d_in[8];
    const float* lin1_b    = (const float*)d_in[9];
    const float* lin2_w    = (const float*)d_in[10];
    const float* lin2_b    = (const float*)d_in[11];
    const float* gk_w      = (const float*)d_in[12];
    const float* gk_b      = (const float*)d_in[13];
    const float* fusion_w  = (const float*)d_in[14];
    const float* fusion_b  = (const float*)d_in[15];
    float* out = (float*)d_out;
    float* ws  = (float*)d_ws;
    (void)in_sizes; (void)n_in; (void)out_size; (void)ws_size;

    float* aqk   = ws + OFF_AQK;
    float* kv    = ws + OFF_KV;
    float* kern2 = ws + OFF_K2O;
    float* kern0 = ws + OFF_KERN0;
    float* kernM = ws + OFF_KERNM;
    float* wwb   = ws + OFF_WW;
    float* wt    = ws + OFF_WT;
    float* F2    = ws + OFF_F2;

    // zero the atomic accumulators (aqk, kv, kern2)
    hipMemsetAsync(ws, 0, ZERO_FLOATS * sizeof(float), stream);

    k_attn_pool<<<2048, 256, 0, stream>>>(attn, aqk);
    k_win_pool<<<32, 640, 0, stream>>>(x, down_w, down_b, kern0, wwb);
    k_mlp<<<1, 64, 0, stream>>>(wwb, lin1_w, lin1_b, lin2_w, lin2_b, wt);
    k_mm576<<<81, 256, 0, stream>>>(kern0, proj_v_w, proj_v_b, kv);
    k_pmm<<<32, 576, 0, stream>>>(aqk, kv, kernM);
    k_mm576<<<81, 256, 0, stream>>>(kernM, proj_out_w, proj_out_b, kern2);
    k_build_F<<<8, 576, 0, stream>>>(kern2, wt, gk_w, gk_b, fusion_w, F2);
    k_conv<<<512, 256, 0, stream>>>(x, F2, fusion_b, out);
}

// Round 2
// 824.009 us; speedup vs baseline: 1.0314x; 1.0314x over previous
//
#include <hip/hip_runtime.h>
#include <cstdint>

// Problem constants
#define NB 8
#define NL 4096
#define NC 64
#define NWIN 4
#define NHEAD 4
#define DD 576   // C*K*K

// ws float offsets
#define OFF_AQK   0         // 128*81 sums (atomic)
#define OFF_KV    10368     // 32*576 (atomic)
#define OFF_K2O   28800     // 32*576 (atomic)
#define ZERO_FLOATS 47232
#define OFF_KERN0 47232     // 32*576
#define OFF_KERNM 65664     // 32*576
#define OFF_WW    84096     // 32
#define OFF_F2    84160     // [b][c][9][64] = 294912

// ---------------------------------------------------------------------------
// K1: adaptive pool attn (128 mats of 1024x1024) -> per-mat 9x9 SUMS (atomic)
// torch bins: elem c in bin p=(c*9)>>10; also in p+1 iff c == ((p+1)<<10)/9.
// Coalesced: lane owns 4 contiguous floats in each of 4 segments (1KB/instr).
// 16 consecutive rows span <=2 row-bins -> 16 static register accumulators,
// LDS atomics once per 16-row chunk (16 per thread total).
// ---------------------------------------------------------------------------
__global__ __launch_bounds__(256) void k_attn_pool(const float* __restrict__ attn,
                                                   float* __restrict__ aqk_sum) {
    __shared__ float accL[81];
    int t = threadIdx.x;
    if (t < 81) accL[t] = 0.f;
    __syncthreads();

    int mat = blockIdx.x >> 4;          // 0..127
    int chunk = blockIdx.x & 15;        // 64 rows each
    int wave = t >> 6, lane = t & 63;
    const float* base = attn + (size_t)mat * 1048576u;

    // per-segment column masks (4 contiguous elems span <=2 col bins)
    float cm0[4][4], cm1[4][4];
    int b0s[4];
#pragma unroll
    for (int s = 0; s < 4; ++s) {
        int c0 = s * 256 + lane * 4;
        int b0 = (c0 * 9) >> 10;
        b0s[s] = b0;
#pragma unroll
        for (int e = 0; e < 4; ++e) {
            int c = c0 + e;
            int p = (c * 9) >> 10;
            int ns = ((p + 1) << 10) / 9;        // start col of bin p+1
            bool sh = (c == ns);                 // shared into bin p+1
            cm0[s][e] = (p == b0) ? 1.f : 0.f;
            cm1[s][e] = ((p == b0 + 1) || (p == b0 && sh)) ? 1.f : 0.f;
        }
    }

    int r0 = chunk * 64 + wave * 16;
    int rb0 = (r0 * 9) >> 10;
    float a00[4] = {0.f, 0.f, 0.f, 0.f};   // [seg]: row-slot0 x col-slot0
    float a01[4] = {0.f, 0.f, 0.f, 0.f};   // row-slot0 x col-slot1
    float a10[4] = {0.f, 0.f, 0.f, 0.f};
    float a11[4] = {0.f, 0.f, 0.f, 0.f};

    for (int rr = 0; rr < 16; ++rr) {
        int r = r0 + rr;
        const float4* rowp = reinterpret_cast<const float4*>(base + (size_t)r * 1024);
        float4 vv[4];
        vv[0] = rowp[lane];
        vv[1] = rowp[64 + lane];
        vv[2] = rowp[128 + lane];
        vv[3] = rowp[192 + lane];
        int rp = (r * 9) >> 10;
        int rs = ((rp + 1) << 10) / 9;
        float mf0 = (rp == rb0) ? 1.f : 0.f;
        float mf1 = ((rp == rb0 + 1) || (rp == rb0 && r == rs)) ? 1.f : 0.f;
#pragma unroll
        for (int s = 0; s < 4; ++s) {
            float cl0 = vv[s].x * cm0[s][0] + vv[s].y * cm0[s][1]
                      + vv[s].z * cm0[s][2] + vv[s].w * cm0[s][3];
            float cl1 = vv[s].x * cm1[s][0] + vv[s].y * cm1[s][1]
                      + vv[s].z * cm1[s][2] + vv[s].w * cm1[s][3];
            a00[s] += cl0 * mf0;
            a01[s] += cl1 * mf0;
            a10[s] += cl0 * mf1;
            a11[s] += cl1 * mf1;
        }
    }

#pragma unroll
    for (int s = 0; s < 4; ++s) {
        int cb = b0s[s];
        atomicAdd(&accL[rb0 * 9 + cb], a00[s]);
        if (cb < 8 && a01[s] != 0.f) atomicAdd(&accL[rb0 * 9 + cb + 1], a01[s]);
        if (rb0 < 8) {
            if (a10[s] != 0.f) atomicAdd(&accL[(rb0 + 1) * 9 + cb], a10[s]);
            if (cb < 8 && a11[s] != 0.f) atomicAdd(&accL[(rb0 + 1) * 9 + cb + 1], a11[s]);
        }
    }
    __syncthreads();
    if (t < 81) atomicAdd(&aqk_sum[mat * 81 + t], accL[t]);
}

// ---------------------------------------------------------------------------
// K2: per-window 32x32 -> 3x3 adaptive pool (kern0 [win][c*9+kk]) and
//     ww[b*4+nw] = sum_c mean(window)*down_w[nw][c] + down_b[nw]
// 1024 threads: t -> (c4 = t&15, j = (t>>4)&31, s = t>>9). float4 coalesced.
// Register bin accumulators [3rb][3cb][4ch]; wave-uniform row branches.
// ---------------------------------------------------------------------------
__global__ __launch_bounds__(1024) void k_win_pool(const float* __restrict__ x,
                                                   const float* __restrict__ down_w,
                                                   const float* __restrict__ down_b,
                                                   float* __restrict__ kern0,
                                                   float* __restrict__ ww) {
    __shared__ float sums[3][3][64];
    __shared__ float tot[64];
    int t = threadIdx.x;
    if (t < 576) ((float*)sums)[t] = 0.f;
    else if (t < 640) tot[t - 576] = 0.f;
    __syncthreads();

    int blk = blockIdx.x;              // b*4+nw
    int b = blk >> 2, nw = blk & 3;
    int wr = nw >> 1, wc = nw & 1;
    int c4 = t & 15, j = (t >> 4) & 31, s = t >> 9;
    const float* xb = x + ((size_t)b * NL + (size_t)(wr * 32) * 64 + wc * 32 + j) * 64 + c4 * 4;

    // col masks for this thread's j (32 -> 3 bins; overlap at j=10, j=21)
    int q = (3 * j) >> 5;
    int js = ((q + 1) << 5) / 3;
    bool csh = (j == js);
    float cw[3];
#pragma unroll
    for (int k = 0; k < 3; ++k)
        cw[k] = ((k == q) || (csh && k == q + 1)) ? 1.f : 0.f;

    float acc[3][3][4];
#pragma unroll
    for (int rb = 0; rb < 3; ++rb)
#pragma unroll
        for (int cb = 0; cb < 3; ++cb)
#pragma unroll
            for (int ch = 0; ch < 4; ++ch) acc[rb][cb][ch] = 0.f;
    float ts[4] = {0.f, 0.f, 0.f, 0.f};

    for (int i = 0; i < 16; ++i) {
        int r = s * 16 + i;            // wave-uniform (s uniform per wave)
        float4 v = *reinterpret_cast<const float4*>(xb + (size_t)r * 4096);
        ts[0] += v.x; ts[1] += v.y; ts[2] += v.z; ts[3] += v.w;
        int rp = (3 * r) >> 5;
        int rsb = ((rp + 1) << 5) / 3;
        bool rsh = (r == rsb);
#pragma unroll
        for (int rb = 0; rb < 3; ++rb) {
            if (rb == rp || (rsh && rb == rp + 1)) {
#pragma unroll
                for (int cb = 0; cb < 3; ++cb) {
                    acc[rb][cb][0] += v.x * cw[cb];
                    acc[rb][cb][1] += v.y * cw[cb];
                    acc[rb][cb][2] += v.z * cw[cb];
                    acc[rb][cb][3] += v.w * cw[cb];
                }
            }
        }
    }

#pragma unroll
    for (int rb = 0; rb < 3; ++rb)
#pragma unroll
        for (int cb = 0; cb < 3; ++cb)
#pragma unroll
            for (int ch = 0; ch < 4; ++ch) {
                float v = acc[rb][cb][ch];
                if (v != 0.f) atomicAdd(&sums[rb][cb][c4 * 4 + ch], v);
            }
#pragma unroll
    for (int ch = 0; ch < 4; ++ch) atomicAdd(&tot[c4 * 4 + ch], ts[ch]);
    __syncthreads();

    if (t < 576) {
        int c = t / 9, rem = t % 9, ki = rem / 3, kj = rem % 3;
        const float cnt0 = 11.f, cnt1 = 12.f;
        float rc = (ki == 1) ? cnt1 : cnt0;
        float cc = (kj == 1) ? cnt1 : cnt0;
        kern0[(size_t)blk * DD + t] = sums[ki][kj][c] / (rc * cc);
    }
    if (t < 64) {
        float v = tot[t] * (1.f / 1024.f) * down_w[nw * 64 + t];
#pragma unroll
        for (int off = 32; off; off >>= 1) v += __shfl_down(v, off);
        if (t == 0) ww[blk] = v + down_b[nw];
    }
}

// ---------------------------------------------------------------------------
// K3a/K3c: out(32x576) += A(32x576) @ W(576x576)^T  (+bias on ic==0), atomics
// ---------------------------------------------------------------------------
__global__ __launch_bounds__(256) void k_mm576(const float* __restrict__ A,
                                               const float* __restrict__ Wm,
                                               const float* __restrict__ bias,
                                               float* __restrict__ out) {
    __shared__ float Ws[64][65];
    __shared__ float As[32][65];
    int oc = blockIdx.x % 9, ic = blockIdx.x / 9;
    int o0 = oc * 64, i0 = ic * 64;
    int t = threadIdx.x;
    for (int idx = t; idx < 64 * 64; idx += 256) {
        int j = idx >> 6, ii = idx & 63;
        Ws[j][ii] = Wm[(size_t)(o0 + j) * DD + i0 + ii];
    }
    for (int idx = t; idx < 32 * 64; idx += 256) {
        int r = idx >> 6, ii = idx & 63;
        As[r][ii] = A[r * DD + i0 + ii];
    }
    __syncthreads();
    int j = t & 63, rg = t >> 6;
    float acc[8];
#pragma unroll
    for (int q = 0; q < 8; ++q) acc[q] = 0.f;
    for (int ii = 0; ii < 64; ++ii) {
        float w = Ws[j][ii];
#pragma unroll
        for (int q = 0; q < 8; ++q) acc[q] += As[rg * 8 + q][ii] * w;
    }
    float bo = (ic == 0) ? bias[o0 + j] : 0.f;
#pragma unroll
    for (int q = 0; q < 8; ++q)
        atomicAdd(&out[(rg * 8 + q) * DD + o0 + j], acc[q] + bo);
}

// ---------------------------------------------------------------------------
// K3b: kernM[b][n][i*144+dh*9+k2] = sum_q aqk_mean[f][k2][q] * kvT[f][q][dh]
// ---------------------------------------------------------------------------
__global__ __launch_bounds__(576) void k_pmm(const float* __restrict__ aqk_sum,
                                             const float* __restrict__ kv,
                                             float* __restrict__ kernM) {
    int blk = blockIdx.x;             // b*4 + n
    int b = blk >> 2, n = blk & 3;
    int d = threadIdx.x;              // 0..575
    int i = d / 144, rem = d % 144, dh = rem / 9, k2 = rem % 9;
    int f = b * 16 + i * 4 + n;
    int sk = (k2 * 1024) / 9, ek = ((k2 + 1) * 1024 + 8) / 9;
    float rlk = (float)(ek - sk);
    const float* aq = aqk_sum + f * 81 + k2 * 9;
    const float* kvp = kv + (b * 4 + i) * DD + n * 144 + dh * 9;
    float acc = 0.f;
#pragma unroll
    for (int q = 0; q < 9; ++q) {
        int sq = (q * 1024) / 9, eq = ((q + 1) * 1024 + 8) / 9;
        float inv = 1.f / (rlk * (float)(eq - sq));
        acc += aq[q] * inv * kvp[q];
    }
    kernM[blk * DD + d] = acc;
}

// ---------------------------------------------------------------------------
// K4: F2[b][d=(c*9+kl)][o] = sum_n fwT[n*64+c][o]*k2s_n + fwT[256+c][o]*g
// fusion_w staged TRANSPOSED in LDS (pitch 65, conflict-free); o = lane ->
// coalesced F2 writes. Tiny MLP folded in (removes a launch).
// ---------------------------------------------------------------------------
__global__ __launch_bounds__(576) void k_build_F(const float* __restrict__ kern2,
                                                 const float* __restrict__ wwb,
                                                 const float* __restrict__ lin1_w,
                                                 const float* __restrict__ lin1_b,
                                                 const float* __restrict__ lin2_w,
                                                 const float* __restrict__ lin2_b,
                                                 const float* __restrict__ gk_w,
                                                 const float* __restrict__ gk_b,
                                                 const float* __restrict__ fusion_w,
                                                 float* __restrict__ F2) {
    __shared__ float fwT[320][65];    // fwT[i][o] = fusion_w[o][i]
    __shared__ float k2L[4 * DD];
    __shared__ float hL[16];
    __shared__ float wt[4];
    int b = blockIdx.x;
    int t = threadIdx.x;

    // stage fusion_w transposed (64x320 f32, flat float4)
    const float4* fw4 = reinterpret_cast<const float4*>(fusion_w);
    for (int idx = t; idx < 5120; idx += 576) {
        int o = idx / 80, i4 = idx % 80;
        float4 v = fw4[idx];
        fwT[i4 * 4 + 0][o] = v.x;
        fwT[i4 * 4 + 1][o] = v.y;
        fwT[i4 * 4 + 2][o] = v.z;
        fwT[i4 * 4 + 3][o] = v.w;
    }
    for (int idx = t; idx < 4 * DD; idx += 576)
        k2L[idx] = kern2[(size_t)b * 4 * DD + idx];
    if (t < 16) {   // MLP hidden
        float h = lin1_b[t];
#pragma unroll
        for (int n = 0; n < 4; ++n) h += wwb[b * 4 + n] * lin1_w[t * 4 + n];
        hL[t] = 0.5f * h * (1.f + erff(h * 0.70710678118654752440f));
    }
    __syncthreads();
    if (t < 4) {    // MLP out -> sigmoid -> weight
        float a = lin2_b[t];
        for (int jj = 0; jj < 16; ++jj) a += hL[jj] * lin2_w[t * 16 + jj];
        wt[t] = 1.f / (1.f + expf(-a));
    }
    __syncthreads();

    int o = t & 63, dg = t >> 6;      // dg 0..8
    float gw0 = gk_w[0], gw1 = gk_w[1], gw2 = gk_w[2], gw3 = gk_w[3];
    float gkb = gk_b[0];
    float w0 = wt[0], w1 = wt[1], w2 = wt[2], w3 = wt[3];
    int c = (dg * 64) / 9, kl = (dg * 64) % 9;
    for (int dd = 0; dd < 64; ++dd) {
        int d = dg * 64 + dd;
        float s0 = k2L[d] * w0;
        float s1 = k2L[DD + d] * w1;
        float s2 = k2L[2 * DD + d] * w2;
        float s3 = k2L[3 * DD + d] * w3;
        float g = gkb + s0 * gw0 + s1 * gw1 + s2 * gw2 + s3 * gw3;
        float val = fwT[c][o] * s0 + fwT[64 + c][o] * s1
                  + fwT[128 + c][o] * s2 + fwT[192 + c][o] * s3
                  + fwT[256 + c][o] * g;
        F2[((size_t)b * DD + d) * 64 + o] = val;
        if (++kl == 9) { kl = 0; ++c; }
    }
}

// ---------------------------------------------------------------------------
// K5: out[b, h*64+w, o] = fusion_b[o] + sum_{c,dk,dl} x[b,h+dk-1,w+dl-1,c]*F2[b,c,dk*3+dl,o]
// ---------------------------------------------------------------------------
__global__ __launch_bounds__(256) void k_conv(const float* __restrict__ x,
                                              const float* __restrict__ F2,
                                              const float* __restrict__ fusion_b,
                                              float* __restrict__ out) {
    __shared__ float As[3][16][68];     // [dk][c&15][w+1]
    __shared__ float Bs[16][9][64];     // [c&15][kl][o]
    int t = threadIdx.x;
    int h = blockIdx.x & 63, b = blockIdx.x >> 6;
    int w0 = (t & 15) * 4;
    int o0 = (t >> 4) * 4;

    float acc[4][4];
#pragma unroll
    for (int wi = 0; wi < 4; ++wi)
#pragma unroll
        for (int oi = 0; oi < 4; ++oi) acc[wi][oi] = 0.f;

    for (int cq = 0; cq < 4; ++cq) {
        __syncthreads();
        for (int idx = t; idx < 16 * 9 * 64; idx += 256) {
            int o = idx & 63; int r = idx >> 6; int kl = r % 9; int cc = r / 9;
            Bs[cc][kl][o] = F2[(((size_t)b * 64 + cq * 16 + cc) * 9 + kl) * 64 + o];
        }
        for (int idx = t; idx < 3 * 64 * 4; idx += 256) {
            int gg = idx & 3; int w = (idx >> 2) & 63; int dk = idx >> 8;
            int hh = h + dk - 1;
            float4 v = make_float4(0.f, 0.f, 0.f, 0.f);
            if (hh >= 0 && hh < 64)
                v = *reinterpret_cast<const float4*>(
                    &x[(((size_t)b * 64 + hh) * 64 + w) * 64 + cq * 16 + gg * 4]);
            As[dk][gg * 4 + 0][w + 1] = v.x;
            As[dk][gg * 4 + 1][w + 1] = v.y;
            As[dk][gg * 4 + 2][w + 1] = v.z;
            As[dk][gg * 4 + 3][w + 1] = v.w;
        }
        if (t < 96) {
            int cc = t & 15; int dk = (t >> 4) % 3; int side = t / 48;
            As[dk][cc][side ? 65 : 0] = 0.f;
        }
        __syncthreads();

#pragma unroll
        for (int dk = 0; dk < 3; ++dk) {
#pragma unroll 4
            for (int cc = 0; cc < 16; ++cc) {
                float4 xa = *reinterpret_cast<const float4*>(&As[dk][cc][w0]);
                float xv[6];
                xv[0] = xa.x; xv[1] = xa.y; xv[2] = xa.z; xv[3] = xa.w;
                xv[4] = As[dk][cc][w0 + 4];
                xv[5] = As[dk][cc][w0 + 5];
#pragma unroll
                for (int dl = 0; dl < 3; ++dl) {
                    float4 bv = *reinterpret_cast<const float4*>(&Bs[cc][dk * 3 + dl][o0]);
#pragma unroll
                    for (int wi = 0; wi < 4; ++wi) {
                        float xx = xv[wi + dl];
                        acc[wi][0] += xx * bv.x;
                        acc[wi][1] += xx * bv.y;
                        acc[wi][2] += xx * bv.z;
                        acc[wi][3] += xx * bv.w;
                    }
                }
            }
        }
    }

    float4 fb = *reinterpret_cast<const float4*>(&fusion_b[o0]);
#pragma unroll
    for (int wi = 0; wi < 4; ++wi) {
        float4 r;
        r.x = acc[wi][0] + fb.x;
        r.y = acc[wi][1] + fb.y;
        r.z = acc[wi][2] + fb.z;
        r.w = acc[wi][3] + fb.w;
        *reinterpret_cast<float4*>(
            &out[(((size_t)b * NL) + h * 64 + w0 + wi) * 64 + o0]) = r;
    }
}

// ---------------------------------------------------------------------------
extern "C" void kernel_launch(void* const* d_in, const int* in_sizes, int n_in,
                              void* d_out, int out_size, void* d_ws, size_t ws_size,
                              hipStream_t stream) {
    const float* x         = (const float*)d_in[0];
    const float* attn      = (const float*)d_in[1];
    const float* proj_v_w  = (const float*)d_in[2];
    const float* proj_v_b  = (const float*)d_in[3];
    const float* proj_out_w= (const float*)d_in[4];
    const float* proj_out_b= (const float*)d_in[5];
    const float* down_w    = (const float*)d_in[6];
    const float* down_b    = (const float*)d_in[7];
    const float* lin1_w    = (const float*)d_in[8];
    const float* lin1_b    = (const float*)d_in[9];
    const float* lin2_w    = (const float*)d_in[10];
    const float* lin2_b    = (const float*)d_in[11];
    const float* gk_w      = (const float*)d_in[12];
    const float* gk_b      = (const float*)d_in[13];
    const float* fusion_w  = (const float*)d_in[14];
    const float* fusion_b  = (const float*)d_in[15];
    float* out = (float*)d_out;
    float* ws  = (float*)d_ws;
    (void)in_sizes; (void)n_in; (void)out_size; (void)ws_size;

    float* aqk   = ws + OFF_AQK;
    float* kv    = ws + OFF_KV;
    float* kern2 = ws + OFF_K2O;
    float* kern0 = ws + OFF_KERN0;
    float* kernM = ws + OFF_KERNM;
    float* wwb   = ws + OFF_WW;
    float* F2    = ws + OFF_F2;

    // zero the atomic accumulators (aqk, kv, kern2)
    hipMemsetAsync(ws, 0, ZERO_FLOATS * sizeof(float), stream);

    k_attn_pool<<<2048, 256, 0, stream>>>(attn, aqk);
    k_win_pool<<<32, 1024, 0, stream>>>(x, down_w, down_b, kern0, wwb);
    k_mm576<<<81, 256, 0, stream>>>(kern0, proj_v_w, proj_v_b, kv);
    k_pmm<<<32, 576, 0, stream>>>(aqk, kv, kernM);
    k_mm576<<<81, 256, 0, stream>>>(kernM, proj_out_w, proj_out_b, kern2);
    k_build_F<<<8, 576, 0, stream>>>(kern2, wwb, lin1_w, lin1_b, lin2_w, lin2_b,
                                     gk_w, gk_b, fusion_w, F2);
    k_conv<<<512, 256, 0, stream>>>(x, F2, fusion_b, out);
}